// Round 4
// baseline (14601.843 us; speedup 1.0000x reference)
//
#include <hip/hip_runtime.h>
#include <cstdint>
#include <cstddef>

static constexpr int BS  = 128;
static constexpr int RAL = 1024;
static constexpr int LAL = 256;
static constexpr int CS  = 256;
static constexpr int VOC = 34;
static constexpr int HFS = 512;
static constexpr int EMB = 256;

typedef float  f32x4  __attribute__((ext_vector_type(4)));
typedef short  bf16x8 __attribute__((ext_vector_type(8)));

static __device__ __forceinline__ float bflo(unsigned int u) {
    return __builtin_bit_cast(float, u << 16);
}
static __device__ __forceinline__ float bfhi(unsigned int u) {
    return __builtin_bit_cast(float, u & 0xffff0000u);
}
static __device__ __forceinline__ unsigned short f2bf(float f) {
    unsigned int x = __builtin_bit_cast(unsigned int, f);
    x = (x + 0x7fffu + ((x >> 16) & 1u)) >> 16;   // RNE
    return (unsigned short)x;
}
static __device__ __forceinline__ float sigf(float x)   { return 1.0f / (1.0f + __expf(-x)); }
static __device__ __forceinline__ float tanhf_(float x) { return 1.0f - 2.0f / (__expf(2.0f * x) + 1.0f); }

// packed bf16 pair dot product: c += lo(a)*lo(b) + hi(a)*hi(b)
#if __has_builtin(__builtin_amdgcn_fdot2_f32_bf16)
typedef __bf16 bf16x2v __attribute__((ext_vector_type(2)));
static __device__ __forceinline__ float dot2bf(unsigned int a, unsigned int b, float c) {
    return __builtin_amdgcn_fdot2_f32_bf16(__builtin_bit_cast(bf16x2v, a),
                                           __builtin_bit_cast(bf16x2v, b), c, false);
}
#else
static __device__ __forceinline__ float dot2bf(unsigned int a, unsigned int b, float c) {
    return c + bflo(a) * bflo(b) + bfhi(a) * bfhi(b);
}
#endif

// ---------------- fp32 -> bf16 conversion (once per launch) ----------------
__global__ void cvt4_kernel(const float4* __restrict__ in, ushort4* __restrict__ out, int n4) {
    int i  = blockIdx.x * blockDim.x + threadIdx.x;
    int st = gridDim.x * blockDim.x;
    for (; i < n4; i += st) {
        float4 v = in[i];
        ushort4 o;
        o.x = f2bf(v.x); o.y = f2bf(v.y); o.z = f2bf(v.z); o.w = f2bf(v.w);
        out[i] = o;
    }
}

// ---------------- val (b,r,c) fp32 -> VT (b,c,r) bf16, 64x64 tiles via LDS ----------------
__global__ __launch_bounds__(256) void transpose_val(const float* __restrict__ val,
                                                     unsigned short* __restrict__ VT) {
    __shared__ float tile[64][68];            // 68-float row stride: 272 B, 16-aligned
    const int b  = blockIdx.y;
    const int rt = blockIdx.x >> 2;           // 16 row tiles
    const int ct = blockIdx.x & 3;            // 4 col tiles
    const int t  = threadIdx.x;

    const float* src = val + (long)b * RAL * CS + (long)(rt * 64) * CS + ct * 64;
    {
        const int rl = t >> 4;                // 0..15
        const int c4 = (t & 15) * 4;
#pragma unroll
        for (int j = 0; j < 4; ++j) {
            int rr = rl + j * 16;
            float4 v = *(const float4*)(src + (long)rr * CS + c4);
            *(float4*)&tile[rr][c4] = v;
        }
    }
    __syncthreads();
    {
        const int cl   = t >> 2;              // 0..63
        const int rseg = t & 3;               // 16-row segment
        unsigned short* dst = VT + (long)b * RAL * CS + (long)(ct * 64 + cl) * RAL + rt * 64;
#pragma unroll
        for (int s = 0; s < 4; ++s) {
            int r0 = rseg * 16 + s * 4;
            ushort4 o;
            o.x = f2bf(tile[r0 + 0][cl]);
            o.y = f2bf(tile[r0 + 1][cl]);
            o.z = f2bf(tile[r0 + 2][cl]);
            o.w = f2bf(tile[r0 + 3][cl]);
            *(ushort4*)(dst + r0) = o;
        }
    }
}

// ---------------- valid-length precompute (mask is a prefix mask) ----------------
__global__ __launch_bounds__(256) void len_kernel(const float* __restrict__ mask, int* __restrict__ Llen) {
    __shared__ int red[256];
    const int b = blockIdx.x, tid = threadIdx.x;
    int c = 0;
    for (int r = tid; r < RAL; r += 256) c += (mask[b * RAL + r] != 0.0f) ? 1 : 0;
    red[tid] = c;
    __syncthreads();
    for (int s = 128; s > 0; s >>= 1) {
        if (tid < s) red[tid] += red[tid + s];
        __syncthreads();
    }
    if (tid == 0) Llen[b] = red[0];
}

// ---------------- fused LSTM cell, 4-way K-split across waves ----------------
__global__ __launch_bounds__(256) void lstm_kernel(
    const unsigned short* __restrict__ p0, int s0,
    const unsigned short* __restrict__ p1, int s1,
    const unsigned short* __restrict__ p2, int s2,
    const unsigned short* __restrict__ p3, int s3,
    const int* __restrict__ yidx, int t,
    const unsigned short* __restrict__ Wih, const unsigned short* __restrict__ Whh,
    const float* __restrict__ bih, const float* __restrict__ bhh,
    float* __restrict__ cst,
    unsigned short* __restrict__ hout)
{
    __shared__ __align__(16) float zp[3][4][64][4];  // [wave-1][gate][lane][r]

    const int tid  = threadIdx.x;
    const int lane = tid & 63;
    const int wv   = tid >> 6;
    const int quad = lane >> 4;
    const int l16  = lane & 15;
    const int j    = blockIdx.x * 16 + l16;
    const int mrow = blockIdx.y * 16 + l16;

    const unsigned short* pa;
    const unsigned short* wb;
    {
        const unsigned short* const ps[4] = {p0, p1, p2, p3};
        const int ss[4] = {s0, s1, s2, s3};
        long rbase;
        if (wv == 0 && yidx) rbase = (long)yidx[mrow * LAL + t] * ss[0];
        else                 rbase = (long)mrow * ss[wv];
        pa = ps[wv] + rbase + quad * 8;
        const unsigned short* Wp = (wv < 2) ? Wih : Whh;
        wb = Wp + (wv & 1) * 256 + quad * 8;
    }

    const unsigned short* wg[4];
#pragma unroll
    for (int g = 0; g < 4; ++g) wg[g] = wb + (long)(g * HFS + j) * HFS;

    f32x4 acc[4];
#pragma unroll
    for (int g = 0; g < 4; ++g) acc[g] = (f32x4)0.0f;

#pragma unroll
    for (int kc = 0; kc < 8; ++kc) {
        bf16x8 a  = *(const bf16x8*)(pa + kc * 32);
        bf16x8 b0 = *(const bf16x8*)(wg[0] + kc * 32);
        bf16x8 b1 = *(const bf16x8*)(wg[1] + kc * 32);
        bf16x8 b2 = *(const bf16x8*)(wg[2] + kc * 32);
        bf16x8 b3 = *(const bf16x8*)(wg[3] + kc * 32);
        acc[0] = __builtin_amdgcn_mfma_f32_16x16x32_bf16(a, b0, acc[0], 0, 0, 0);
        acc[1] = __builtin_amdgcn_mfma_f32_16x16x32_bf16(a, b1, acc[1], 0, 0, 0);
        acc[2] = __builtin_amdgcn_mfma_f32_16x16x32_bf16(a, b2, acc[2], 0, 0, 0);
        acc[3] = __builtin_amdgcn_mfma_f32_16x16x32_bf16(a, b3, acc[3], 0, 0, 0);
    }

    if (wv != 0) {
#pragma unroll
        for (int g = 0; g < 4; ++g)
            *(f32x4*)&zp[wv - 1][g][lane][0] = acc[g];
    }
    __syncthreads();
    if (wv == 0) {
#pragma unroll
        for (int g = 0; g < 4; ++g) {
            acc[g] += *(const f32x4*)&zp[0][g][lane][0];
            acc[g] += *(const f32x4*)&zp[1][g][lane][0];
            acc[g] += *(const f32x4*)&zp[2][g][lane][0];
        }
        const float bI = bih[j]           + bhh[j];
        const float bF = bih[HFS + j]     + bhh[HFS + j];
        const float bG = bih[2 * HFS + j] + bhh[2 * HFS + j];
        const float bO = bih[3 * HFS + j] + bhh[3 * HFS + j];
#pragma unroll
        for (int r = 0; r < 4; ++r) {
            int m   = blockIdx.y * 16 + quad * 4 + r;
            int idx = m * HFS + j;
            float iv = sigf(acc[0][r] + bI);
            float fv = sigf(acc[1][r] + bF);
            float gv = tanhf_(acc[2][r] + bG);
            float ov = sigf(acc[3][r] + bO);
            float cn = fv * cst[idx] + iv * gv;
            cst[idx] = cn;
            hout[idx] = f2bf(ov * tanhf_(cn));
        }
    }
}

// ---------------- attention: query + masked softmax + context + logits ----------------
// one block (1024 threads, 16 waves) per batch element.
// TIER 2: key bf16 (b,r,c) + VT bf16 (b,c,r), dot2 path.  TIER 0: fp32 key/val.
template <int TIER>
__global__ __launch_bounds__(1024) void attn_kernel(
    const void* __restrict__ keyp, const void* __restrict__ valp,
    const int* __restrict__ Llen,
    const unsigned short* __restrict__ hbv,
    const unsigned short* __restrict__ Wqb,     // (256,512) bf16
    const float* __restrict__ bq,
    const float* __restrict__ Wc, const float* __restrict__ bc,
    unsigned short* __restrict__ ctxbf,
    float* __restrict__ outp, int t)
{
    __shared__ __align__(16) float xcat[HFS + CS];     // hb fp32 | ctx fp32 (for logits)
    __shared__ __align__(16) unsigned short hb_bf[HFS];
    __shared__ __align__(16) unsigned short q_bf[CS];
    __shared__ __align__(16) float q_lds[CS];          // fp32 q (TIER0)
    __shared__ __align__(16) float e_lds[RAL];
    __shared__ __align__(16) unsigned short ew[RAL];   // softmax weights bf16, zero-padded
    __shared__ __align__(16) float ctxp[16][CS];       // TIER0 partials
    __shared__ float red[32];

    const int tid = threadIdx.x;
    const int b   = blockIdx.x;
    const int L   = Llen[b];

    if (tid < HFS) {
        unsigned short h = hbv[b * HFS + tid];
        hb_bf[tid] = h;
        xcat[tid]  = bflo((unsigned int)h);
    }
    __syncthreads();

    // ---- query: 4 threads per output col ----
    {
        const int c  = tid >> 2;
        const int jj = tid & 3;
        const unsigned short* wr = Wqb + (long)c * HFS + jj * 128;
        float qa = 0.0f;
        if (TIER == 2) {
            const unsigned short* hr = &hb_bf[jj * 128];
#pragma unroll
            for (int k = 0; k < 128; k += 8) {
                uint4 wu = *(const uint4*)(wr + k);
                uint4 hu = *(const uint4*)(hr + k);
                qa = dot2bf(wu.x, hu.x, qa);
                qa = dot2bf(wu.y, hu.y, qa);
                qa = dot2bf(wu.z, hu.z, qa);
                qa = dot2bf(wu.w, hu.w, qa);
            }
        } else {
            const float* xr = &xcat[jj * 128];
#pragma unroll
            for (int k = 0; k < 128; k += 8) {
                uint4 u = *(const uint4*)(wr + k);
                float4 h0 = *(const float4*)(xr + k);
                float4 h1 = *(const float4*)(xr + k + 4);
                qa += bflo(u.x) * h0.x + bfhi(u.x) * h0.y
                    + bflo(u.y) * h0.z + bfhi(u.y) * h0.w
                    + bflo(u.z) * h1.x + bfhi(u.z) * h1.y
                    + bflo(u.w) * h1.z + bfhi(u.w) * h1.w;
            }
        }
        qa += __shfl_xor(qa, 1);
        qa += __shfl_xor(qa, 2);
        if (jj == 0) {
            float qv = qa + bq[c];
            if (TIER == 2) q_bf[c] = f2bf(qv);
            else           q_lds[c] = qv;
        }
    }
    __syncthreads();

    // ---- energy: 8 threads per row, 128 rows per pass ----
    {
        const int jj   = tid & 7;
        const int rloc = tid >> 3;
        for (int r0 = 0; r0 < L; r0 += 128) {
            const int r = r0 + rloc;
            float acc = 0.0f, acc1 = 0.0f;
            if (r < L) {
                if (TIER == 2) {
                    const unsigned short* kp = (const unsigned short*)keyp + ((long)b * RAL + r) * CS + jj * 32;
                    const unsigned short* qp = &q_bf[jj * 32];
#pragma unroll
                    for (int i = 0; i < 4; ++i) {
                        uint4 ku = *(const uint4*)(kp + i * 8);
                        uint4 qu = *(const uint4*)(qp + i * 8);
                        acc  = dot2bf(ku.x, qu.x, acc);
                        acc1 = dot2bf(ku.y, qu.y, acc1);
                        acc  = dot2bf(ku.z, qu.z, acc);
                        acc1 = dot2bf(ku.w, qu.w, acc1);
                    }
                    acc += acc1;
                } else {
                    const float* kp = (const float*)keyp + ((long)b * RAL + r) * CS + jj * 32;
#pragma unroll
                    for (int i = 0; i < 8; ++i) {
                        float4 kv = *(const float4*)(kp + i * 4);
                        float4 qa = *(const float4*)&q_lds[jj * 32 + i * 4];
                        acc += kv.x * qa.x + kv.y * qa.y + kv.z * qa.z + kv.w * qa.w;
                    }
                }
            }
            acc += __shfl_xor(acc, 1);
            acc += __shfl_xor(acc, 2);
            acc += __shfl_xor(acc, 4);
            if (jj == 0 && r < L) e_lds[r] = acc;
        }
    }
    __syncthreads();

    // ---- softmax ----
    float pm = (tid < L) ? e_lds[tid] : -1e30f;
#pragma unroll
    for (int s = 32; s > 0; s >>= 1) pm = fmaxf(pm, __shfl_xor(pm, s));
    if ((tid & 63) == 0) red[tid >> 6] = pm;
    __syncthreads();
    float M = red[0];
#pragma unroll
    for (int i = 1; i < 16; ++i) M = fmaxf(M, red[i]);

    float ps = 0.0f;
    if (tid < L) {
        float v = __expf(e_lds[tid] - M);
        e_lds[tid] = v;
        ew[tid] = f2bf(v);
        ps = v;
    } else {
        ew[tid] = 0;
    }
#pragma unroll
    for (int s = 32; s > 0; s >>= 1) ps += __shfl_xor(ps, s);
    if ((tid & 63) == 0) red[16 + (tid >> 6)] = ps;
    __syncthreads();
    float S = 0.0f;
#pragma unroll
    for (int i = 0; i < 16; ++i) S += red[16 + i];
    const float invS = 1.0f / S;

    // ---- context ----
    if (TIER == 2) {
        // 4 threads per channel, each owns a contiguous 256-row quarter of VT[b][c][:]
        const int c  = tid >> 2;
        const int jj = tid & 3;
        const unsigned short* vtb = (const unsigned short*)valp + (long)b * RAL * CS + (long)c * RAL + jj * 256;
        const unsigned short* wp  = &ew[jj * 256];
        float a0 = 0.0f, a1 = 0.0f;
#pragma unroll 4
        for (int rr = 0; rr < 256; rr += 8) {
            uint4 vu = *(const uint4*)(vtb + rr);
            uint4 wu = *(const uint4*)(wp + rr);
            a0 = dot2bf(vu.x, wu.x, a0);
            a1 = dot2bf(vu.y, wu.y, a1);
            a0 = dot2bf(vu.z, wu.z, a0);
            a1 = dot2bf(vu.w, wu.w, a1);
        }
        float a = a0 + a1;
        a += __shfl_xor(a, 1);
        a += __shfl_xor(a, 2);
        if (jj == 0) {
            float cv = a * invS;
            xcat[HFS + c] = cv;
            ctxbf[b * CS + c] = f2bf(cv);
        }
    } else {
        const int wv = tid >> 6;
        const int c4 = (tid & 63) * 4;
        float a0 = 0.f, a1 = 0.f, a2 = 0.f, a3 = 0.f;
        const float* vb = (const float*)valp + (long)b * RAL * CS + c4;
        int r = wv;
        for (; r + 48 < L; r += 64) {
            float4 v0 = *(const float4*)(vb + (long)(r)      * CS);
            float4 v1 = *(const float4*)(vb + (long)(r + 16) * CS);
            float4 v2 = *(const float4*)(vb + (long)(r + 32) * CS);
            float4 v3 = *(const float4*)(vb + (long)(r + 48) * CS);
            float w0 = e_lds[r], w1 = e_lds[r + 16], w2 = e_lds[r + 32], w3 = e_lds[r + 48];
            a0 += w0 * v0.x + w1 * v1.x + w2 * v2.x + w3 * v3.x;
            a1 += w0 * v0.y + w1 * v1.y + w2 * v2.y + w3 * v3.y;
            a2 += w0 * v0.z + w1 * v1.z + w2 * v2.z + w3 * v3.z;
            a3 += w0 * v0.w + w1 * v1.w + w2 * v2.w + w3 * v3.w;
        }
        for (; r < L; r += 16) {
            float4 v = *(const float4*)(vb + (long)r * CS);
            float w = e_lds[r];
            a0 += w * v.x; a1 += w * v.y; a2 += w * v.z; a3 += w * v.w;
        }
        float4 out4 = {a0, a1, a2, a3};
        *(float4*)&ctxp[wv][c4] = out4;
    }
    __syncthreads();

    if (TIER != 2) {
        if (tid < CS) {
            float cv = 0.0f;
#pragma unroll
            for (int w = 0; w < 16; ++w) cv += ctxp[w][tid];
            cv *= invS;
            xcat[HFS + tid] = cv;
            ctxbf[b * CS + tid] = f2bf(cv);
        }
        __syncthreads();
    }

    // ---- logits: 8 threads per vocab entry ----
    if (tid < VOC * 8) {
        const int v   = tid >> 3;
        const int jj2 = tid & 7;
        const float* wr = Wc + (long)v * (HFS + CS) + jj2 * 96;
        const float* xr = &xcat[jj2 * 96];
        float part = 0.0f;
#pragma unroll
        for (int i = 0; i < 24; ++i) {
            float4 wv4 = *(const float4*)(wr + i * 4);
            float4 xv  = *(const float4*)(xr + i * 4);
            part += wv4.x * xv.x + wv4.y * xv.y + wv4.z * xv.z + wv4.w * xv.w;
        }
        part += __shfl_xor(part, 1);
        part += __shfl_xor(part, 2);
        part += __shfl_xor(part, 4);
        if (jj2 == 0)
            outp[((long)b * LAL + t) * VOC + v] = part + bc[v];
    }
}

// ---------------- host ----------------
extern "C" void kernel_launch(void* const* d_in, const int* in_sizes, int n_in,
                              void* d_out, int out_size, void* d_ws, size_t ws_size,
                              hipStream_t stream)
{
    (void)in_sizes; (void)n_in; (void)out_size;
    const float* keyf  = (const float*)d_in[0];
    const float* valf  = (const float*)d_in[1];
    const float* mask  = (const float*)d_in[2];
    const float* embf  = (const float*)d_in[3];
    const float* WihAf = (const float*)d_in[4];
    const float* WhhAf = (const float*)d_in[5];
    const float* bihA  = (const float*)d_in[6];
    const float* bhhA  = (const float*)d_in[7];
    const float* WihBf = (const float*)d_in[8];
    const float* WhhBf = (const float*)d_in[9];
    const float* bihB  = (const float*)d_in[10];
    const float* bhhB  = (const float*)d_in[11];
    const float* Wqf   = (const float*)d_in[12];
    const float* bq    = (const float*)d_in[13];
    const float* Wc    = (const float*)d_in[14];
    const float* bc    = (const float*)d_in[15];
    const int*   y     = (const int*)d_in[16];
    float* outp = (float*)d_out;

    size_t off = 0;
    auto take = [&](size_t bytes) -> void* {
        void* p = (char*)d_ws + off;
        off += (bytes + 255) & ~(size_t)255;
        return p;
    };

    // zero-initialized state block
    unsigned short* ha    = (unsigned short*)take((size_t)2 * BS * HFS * 2);
    unsigned short* hbuf  = (unsigned short*)take((size_t)2 * BS * HFS * 2);
    float*          ca    = (float*)take((size_t)BS * HFS * 4);
    float*          cbuf  = (float*)take((size_t)BS * HFS * 4);
    unsigned short* ctxbf = (unsigned short*)take((size_t)BS * CS * 2);
    size_t stateBytes = off;

    int*            Llen  = (int*)take((size_t)BS * 4);
    unsigned short* embb  = (unsigned short*)take((size_t)VOC * EMB * 2);
    unsigned short* WihAb = (unsigned short*)take((size_t)4 * HFS * HFS * 2);
    unsigned short* WhhAb = (unsigned short*)take((size_t)4 * HFS * HFS * 2);
    unsigned short* WihBb = (unsigned short*)take((size_t)4 * HFS * HFS * 2);
    unsigned short* WhhBb = (unsigned short*)take((size_t)4 * HFS * HFS * 2);
    unsigned short* Wqb   = (unsigned short*)take((size_t)CS * HFS * 2);

    // --- KV tiers ---
    // A2: key-bf16 + VT in ws.  B2: VT in ws, key-bf16 overwrites val's dead fp32
    //     input (transpose reads valf BEFORE key cvt writes d_in[1]; stream order).
    // 0 : fp32 key/val straight from inputs.
    const size_t kvBytes = (size_t)BS * RAL * CS * 2;   // 64 MiB each
    unsigned short* keyb = nullptr;
    unsigned short* VT   = nullptr;
    int tier = 0;
    bool keyInVal = false;
    if (off + 2 * (kvBytes + 256) <= ws_size) {
        keyb = (unsigned short*)take(kvBytes);
        VT   = (unsigned short*)take(kvBytes);
        tier = 2;
    } else if (off + kvBytes + 256 <= ws_size) {
        VT   = (unsigned short*)take(kvBytes);
        keyb = (unsigned short*)d_in[1];
        tier = 2;
        keyInVal = true;
    }

    hipMemsetAsync(d_ws, 0, stateBytes, stream);
    len_kernel<<<dim3(BS), dim3(256), 0, stream>>>(mask, Llen);

    auto cvt = [&](const float* src, unsigned short* dst, long n) {
        int n4 = (int)(n / 4);
        int blocks = (n4 + 255) / 256;
        if (blocks > 8192) blocks = 8192;
        cvt4_kernel<<<dim3(blocks), dim3(256), 0, stream>>>((const float4*)src, (ushort4*)dst, n4);
    };
    cvt(embf,  embb,  (long)VOC * EMB);
    cvt(WihAf, WihAb, (long)4 * HFS * HFS);
    cvt(WhhAf, WhhAb, (long)4 * HFS * HFS);
    cvt(WihBf, WihBb, (long)4 * HFS * HFS);
    cvt(WhhBf, WhhBb, (long)4 * HFS * HFS);
    cvt(Wqf,   Wqb,   (long)CS * HFS);
    if (tier == 2) {
        // transpose must precede key cvt when key lands in val's input buffer
        transpose_val<<<dim3(64, BS), dim3(256), 0, stream>>>(valf, VT);
        cvt(keyf, keyb, (long)BS * RAL * CS);
        (void)keyInVal;
    }

    for (int t = 0; t < LAL; ++t) {
        unsigned short* haIn  = ha   + (t & 1) * (BS * HFS);
        unsigned short* haOut = ha   + ((t + 1) & 1) * (BS * HFS);
        unsigned short* hbIn  = hbuf + (t & 1) * (BS * HFS);
        unsigned short* hbOut = hbuf + ((t + 1) & 1) * (BS * HFS);

        lstm_kernel<<<dim3(32, 8), dim3(256), 0, stream>>>(
            embb, EMB, ctxbf, CS, haIn, HFS, haIn + 256, HFS,
            y, t, WihAb, WhhAb, bihA, bhhA, ca, haOut);

        lstm_kernel<<<dim3(32, 8), dim3(256), 0, stream>>>(
            haOut, HFS, haOut + 256, HFS, hbIn, HFS, hbIn + 256, HFS,
            nullptr, t, WihBb, WhhBb, bihB, bhhB, cbuf, hbOut);

        if (tier == 2)
            attn_kernel<2><<<dim3(BS), dim3(1024), 0, stream>>>(
                keyb, VT, Llen, hbOut, Wqb, bq, Wc, bc, ctxbf, outp, t);
        else
            attn_kernel<0><<<dim3(BS), dim3(1024), 0, stream>>>(
                keyf, valf, Llen, hbOut, Wqb, bq, Wc, bc, ctxbf, outp, t);
    }
}